// Round 21
// baseline (246.480 us; speedup 1.0000x reference)
//
#include <hip/hip_runtime.h>
#include <cfloat>
#include <stdint.h>

// VQ argmin via exact-split f16 MFMA GEMM — R21: 32x32x16 MFMA shape on the
// R20 structure (A via LDS once/block, B direct, 4 blocks/CU). Same granule
// arrays (zero prep changes): 32x32 fragments index the k8 granules with
// quad' = kh*2 + (lane>>5), rows by lane&31. C/D map for 32x32 is HW-verified
// (m74/m101); A/B map is the direct analog of the m120-verified 16x16 map.
// 24 MFMAs/wave/stage @ 8 cyc replace 48 @ 4.6 (12% less pipe time, half the
// issue slots; 2382 vs 2075 TF ubench ceiling).
// cross = z.e as 3-term f16 GEMM: zh*eh + zh*el + zl*eh, e' = e*2^13 (exact
// pow2), dist = fp32(zsq - acc*2^-12) — identical quantization to all passers.
#define KC 8192
#define NQ 8192
#define DD 256
#define NSTAGE 8
#define NT 64              // total k-tiles of 128 codes
#define MT 32              // A prep tiles (256 rows each)

typedef _Float16 f16;
typedef _Float16 half8 __attribute__((ext_vector_type(8)));
typedef float floatx16 __attribute__((ext_vector_type(16)));

// ---- workspace maps ----
#define WS_AH   0
#define WS_AL   4194304
#define WS_BH   8388608
#define WS_BL2  10485760
#define WS_PART2 12582912
#define WS_BL1  12582912
#define WS_PART1 16777216
#define WS_NEED_1PASS 20971520ull

// LDS: A stage buffer. Quad regions padded 2048->2064 B to stagger banks.
#define AQ 2064
#define AL_OFF (4 * AQ)            // 8256: lo region
#define SMEM_BYTES (8 * AQ)        // 16512

// ---- device helpers (R4..R20-verified bodies) ----
__device__ __forceinline__ void prep_b_body(const float* __restrict__ cb,
                                            f16* __restrict__ Bh, f16* __restrict__ Bl,
                                            int kofs, int gid) {
    int n = gid & 127;
    int q = (gid >> 7) & 3;
    int s = (gid >> 9) & 7;
    int ntl = gid >> 12;
    int K = kofs + ntl * 128 + n;
    int d0 = s * 32 + q * 8;
    const float4 v0 = *(const float4*)(cb + (size_t)K * DD + d0);
    const float4 v1 = *(const float4*)(cb + (size_t)K * DD + d0 + 4);
    float vv[8] = {v0.x, v0.y, v0.z, v0.w, v1.x, v1.y, v1.z, v1.w};
    half8 eh8, el8;
    #pragma unroll
    for (int j = 0; j < 8; ++j) {
        float e = vv[j] * 8192.0f;               // exact pow2 scale
        f16 h = (f16)e;
        eh8[j] = h;
        el8[j] = (f16)(e - (float)h);
    }
    *(half8*)(Bh + (size_t)gid * 8) = eh8;
    *(half8*)(Bl + (size_t)gid * 8) = el8;
}

// Vectorized A-prep (R20-verified): bit-identical granules, float4 along t.
__device__ __forceinline__ void prep_a_vec_body(const float* __restrict__ z,
                                                f16* __restrict__ Ah, f16* __restrict__ Al,
                                                int bid, int tid) {
    const int mt = bid >> 3;
    const int s  = bid & 7;
    const int q  = tid >> 6;
    const int lane = tid & 63;
    const int r0 = lane * 4;
    const int Q0 = mt * 256;
    const int b = Q0 >> 10;
    const int t0 = (Q0 & 1023) + r0;
    const float* zp = z + (size_t)b * (DD * 1024) + t0;
    const int d0 = s * 32 + q * 8;
    float4 v[8];
    #pragma unroll
    for (int j = 0; j < 8; ++j)
        v[j] = *(const float4*)(zp + (size_t)(d0 + j) * 1024);
    const size_t gbase = (((size_t)(mt * 8 + s) * 4 + q) * 256 + r0);
    #pragma unroll
    for (int dq = 0; dq < 4; ++dq) {
        half8 zh8, zl8;
        #pragma unroll
        for (int j = 0; j < 8; ++j) {
            float vv = (dq == 0) ? v[j].x : (dq == 1) ? v[j].y : (dq == 2) ? v[j].z : v[j].w;
            f16 h = (f16)vv;
            zh8[j] = h;
            zl8[j] = (f16)(vv - (float)h);       // exact fp32 residual
        }
        *(half8*)(Ah + (gbase + dq) * 8) = zh8;
        *(half8*)(Al + (gbase + dq) * 8) = zl8;
    }
}

__device__ __forceinline__ void zsq_body(const float* __restrict__ z,
                                         float* __restrict__ zsq, int q) {
    int b = q >> 10, t = q & 1023;
    const float* p = z + (size_t)b * (DD * 1024) + t;
    float s0 = 0.f, s1 = 0.f;
    #pragma unroll 8
    for (int d = 0; d < 128; ++d) { float v = p[(size_t)d * 1024]; s0 = fmaf(v, v, s0); }
    #pragma unroll 8
    for (int d = 128; d < 256; ++d) { float v = p[(size_t)d * 1024]; s1 = fmaf(v, v, s1); }
    zsq[q] = s0 + s1;    // identical chain to R1..R20 passers
}

// ---- fused prep: blocks [0,1024) B | [1024,1280) A-vec | [1280,1312) zsq ----
__global__ void vq_prep_all(const float* __restrict__ z, const float* __restrict__ cb,
                            f16* __restrict__ Ah, f16* __restrict__ Al,
                            f16* __restrict__ Bh, f16* __restrict__ Bl,
                            float* __restrict__ zsq) {
    int bid = blockIdx.x;
    int tid = threadIdx.x;
    if (bid < 1024) {
        prep_b_body(cb, Bh, Bl, 0, bid * 256 + tid);
    } else if (bid < 1280) {
        prep_a_vec_body(z, Ah, Al, bid - 1024, tid);
    } else {
        zsq_body(z, zsq, (bid - 1280) * 256 + tid);
    }
}

// standalone preps for the 2-pass fallback
__global__ void vq_prep_a(const float* __restrict__ z,
                          f16* __restrict__ Ah, f16* __restrict__ Al) {
    prep_a_vec_body(z, Ah, Al, blockIdx.x, threadIdx.x);
}
__global__ void vq_prep_b(const float* __restrict__ cb,
                          f16* __restrict__ Bh, f16* __restrict__ Bl, int kofs) {
    prep_b_body(cb, Bh, Bl, kofs, blockIdx.x * 256 + threadIdx.x);
}
__global__ void vq_zsq(const float* __restrict__ z, float* __restrict__ zsq) {
    zsq_body(z, zsq, blockIdx.x * 256 + threadIdx.x);
}

// ---- main GEMM: 128x128 block, 2x2 waves of 64x64, 32x32x16 MFMA ----
__global__ __launch_bounds__(256, 4)
void vq_gemm17(const f16* __restrict__ Ah, const f16* __restrict__ Al,
               const f16* __restrict__ Bh, const f16* __restrict__ Bl,
               const float* __restrict__ zsq, unsigned long long* __restrict__ part_p,
               int kofs) {
    // Swizzle (R12/R18/R20-verified): per XCD, 8-ntl B chunks x 8 mh2 A tiles.
    const int flat = blockIdx.x;
    const int xcd = flat & 7;
    const int idx = flat >> 3;
    const int mh2 = xcd * 8 + ((idx >> 3) & 7);     // 0..63, 128-row tile
    const int ntl = (idx >> 6) * 8 + (idx & 7);     // 0..63 / 0..31
    const int tid = threadIdx.x;
    const int lane = tid & 63;
    const int wv = tid >> 6;
    const int wm = wv >> 1, wn = wv & 1;            // 2x2 waves of 64x64
    const int l32 = lane & 31;
    const int kh5 = lane >> 5;                      // k8-within-k16 selector

    __shared__ __attribute__((aligned(16))) char smem[SMEM_BYTES];

    floatx16 acc[2][2];                             // [mi][nj] 32x32 tiles
    #pragma unroll
    for (int i = 0; i < 2; ++i)
        #pragma unroll
        for (int j = 0; j < 2; ++j) acc[i][j] = (floatx16)0.f;

    const int mt = mh2 >> 1;
    const int r0 = (mh2 & 1) * 128;
    // B granule base for this lane (n = wn*64 + nj*32 + l32; quad' supplied per kh)
    const size_t bln = (size_t)(wn * 64 + l32) * 8;

    for (int s = 0; s < NSTAGE; ++s) {
        __syncthreads();   // previous stage's A fully consumed
        // ---- stage A into LDS: 16 x 1KB chunks (hi 8, lo 8), 4 per wave ----
        #pragma unroll
        for (int i = 0; i < 4; ++i) {
            int c = wv * 4 + i;                 // wave-uniform chunk id
            int hi = c >> 3;                    // 0: Ah, 1: Al
            int qd = (c >> 1) & 3;
            int hf = c & 1;
            const char* gsrc = (const char*)(hi ? Al : Ah)
                + (((size_t)(mt * 8 + s) * 4 + qd) * 4096) + (size_t)r0 * 16 + hf * 1024;
            int ldsoff = hi * AL_OFF + qd * AQ + hf * 1024;
            __builtin_amdgcn_global_load_lds(
                (const __attribute__((address_space(1))) void*)(gsrc + lane * 16),
                (__attribute__((address_space(3))) void*)(smem + ldsoff),
                16, 0, 0);
        }
        // ---- B fragments direct from global (issued before the barrier drain) ----
        // B[n=lane&31][k=kh*16 + (lane>>5)*8 + j] -> granule quad' = kh*2 + kh5
        half8 bhf[2][2], blf[2][2];                 // [kh][nj]
        #pragma unroll
        for (int kh = 0; kh < 2; ++kh) {
            const size_t gq = ((size_t)(ntl * 8 + s) * 4 + kh * 2 + kh5) * 1024 + bln;
            #pragma unroll
            for (int nj = 0; nj < 2; ++nj) {
                bhf[kh][nj] = *(const half8*)(Bh + gq + nj * 256);
                blf[kh][nj] = *(const half8*)(Bl + gq + nj * 256);
            }
        }
        __syncthreads();   // vmcnt(0) drain -> A staged, B in registers
        // ---- per-kh: A frags from LDS + 12 term-major MFMAs ----
        #pragma unroll
        for (int kh = 0; kh < 2; ++kh) {
            half8 av[2], aw[2];
            #pragma unroll
            for (int mi = 0; mi < 2; ++mi) {
                int ro = (kh * 2 + kh5) * AQ + (wm * 64 + mi * 32 + l32) * 16;
                av[mi] = *(const half8*)(smem + ro);
                aw[mi] = *(const half8*)(smem + AL_OFF + ro);
            }
            #pragma unroll
            for (int mi = 0; mi < 2; ++mi)
                #pragma unroll
                for (int nj = 0; nj < 2; ++nj)
                    acc[mi][nj] = __builtin_amdgcn_mfma_f32_32x32x16_f16(av[mi], bhf[kh][nj], acc[mi][nj], 0, 0, 0);
            #pragma unroll
            for (int mi = 0; mi < 2; ++mi)
                #pragma unroll
                for (int nj = 0; nj < 2; ++nj)
                    acc[mi][nj] = __builtin_amdgcn_mfma_f32_32x32x16_f16(av[mi], blf[kh][nj], acc[mi][nj], 0, 0, 0);
            #pragma unroll
            for (int mi = 0; mi < 2; ++mi)
                #pragma unroll
                for (int nj = 0; nj < 2; ++nj)
                    acc[mi][nj] = __builtin_amdgcn_mfma_f32_32x32x16_f16(aw[mi], bhf[kh][nj], acc[mi][nj], 0, 0, 0);
        }
    }

    // ---- epilogue: verified 32x32 C/D map (col=lane&31, row=(reg&3)+8(reg>>2)+4(lane>>5)) ----
    __syncthreads();                              // reuse smem for kbuf
    unsigned long long* kbuf = (unsigned long long*)smem;   // [2][128]
    const int kb = kofs + ntl * 128 + wn * 64;
    #pragma unroll
    for (int mi = 0; mi < 2; ++mi) {
        #pragma unroll
        for (int reg = 0; reg < 16; ++reg) {
            int row = (reg & 3) + 8 * (reg >> 2) + 4 * kh5;
            int qlocal = wm * 64 + mi * 32 + row;
            float zq = zsq[mh2 * 128 + qlocal];
            float bd = FLT_MAX; int bk = 0;
            #pragma unroll
            for (int nj = 0; nj < 2; ++nj) {        // ascending k: '<' keeps lowest
                float dd = zq - acc[mi][nj][reg] * 0x1p-12f;  // single fp32 rounding
                int kk = kb + nj * 32 + l32;
                if (dd < bd || (dd == bd && kk < bk)) { bd = dd; bk = kk; }
            }
            #pragma unroll
            for (int mm = 1; mm <= 16; mm <<= 1) {  // 32-lane butterfly (same q: masks<32)
                float od = __shfl_xor(bd, mm, 64);
                int ok = __shfl_xor(bk, mm, 64);
                if (od < bd || (od == bd && ok < bk)) { bd = od; bk = ok; }
            }
            if (l32 == 0)
                kbuf[wn * 128 + qlocal] =
                    ((unsigned long long)__float_as_uint(bd) << 32) | (unsigned int)bk;
        }
    }
    __syncthreads();
    if (tid < 128) {
        unsigned long long k0 = kbuf[tid];
        unsigned long long k1 = kbuf[128 + tid];
        unsigned long long key = (k1 < k0) ? k1 : k0;
        part_p[(size_t)ntl * NQ + mh2 * 128 + tid] = key;   // coalesced 1KB store
    }
}

__global__ void vq_reduce64(const unsigned long long* __restrict__ part,
                            int* __restrict__ out) {
    int q = blockIdx.x * 256 + threadIdx.x;
    unsigned long long best = part[q];
    #pragma unroll 8
    for (int s = 1; s < NT; ++s) {                  // coalesced per-row reads
        unsigned long long k2 = part[(size_t)s * NQ + q];
        if (k2 < best) best = k2;
    }
    out[q] = (int)(best & 0xFFFFFFFFull);
}

extern "C" void kernel_launch(void* const* d_in, const int* in_sizes, int n_in,
                              void* d_out, int out_size, void* d_ws, size_t ws_size,
                              hipStream_t stream) {
    const float* z  = (const float*)d_in[0];   // (8, 256, 1024) fp32
    const float* cb = (const float*)d_in[1];   // (8192, 256) fp32
    char* ws = (char*)d_ws;
    f16* Ah = (f16*)(ws + WS_AH);
    f16* Al = (f16*)(ws + WS_AL);
    // zsq parked in d_out (32 KB): read by gemm, overwritten by reduce.
    float* zsq = (float*)d_out;
    int* out = (int*)d_out;

    if (ws_size >= WS_NEED_1PASS) {
        f16* Bh = (f16*)(ws + WS_BH);
        f16* Bl = (f16*)(ws + WS_BL1);
        unsigned long long* part = (unsigned long long*)(ws + WS_PART1);
        vq_prep_all<<<1312, 256, 0, stream>>>(z, cb, Ah, Al, Bh, Bl, zsq);
        vq_gemm17<<<4096, 256, 0, stream>>>(Ah, Al, Bh, Bl, zsq, part, 0);
        vq_reduce64<<<NQ / 256, 256, 0, stream>>>(part, out);
    } else {
        // 2-pass fallback under the proven 16.875 MB floor (B buffer reused)
        f16* Bh = (f16*)(ws + WS_BH);
        f16* Bl = (f16*)(ws + WS_BL2);
        unsigned long long* part = (unsigned long long*)(ws + WS_PART2);
        vq_zsq<<<NQ / 256, 256, 0, stream>>>(z, zsq);
        vq_prep_a<<<256, 256, 0, stream>>>(z, Ah, Al);
        for (int p = 0; p < 2; ++p) {
            int kofs = p * 4096;
            vq_prep_b<<<512, 256, 0, stream>>>(cb, Bh, Bl, kofs);
            vq_gemm17<<<2048, 256, 0, stream>>>(Ah, Al, Bh, Bl, zsq,
                                                part + (size_t)p * 32 * NQ, kofs);
        }
        vq_reduce64<<<NQ / 256, 256, 0, stream>>>(part, out);
    }
}

// Round 22
// 204.882 us; speedup vs baseline: 1.2030x; 1.2030x over previous
//
#include <hip/hip_runtime.h>
#include <cfloat>
#include <stdint.h>

// VQ argmin via exact-split f16 MFMA GEMM — FINAL (R20 configuration, best
// verified: 198.8us total; gemm 117.5us = 875 TF, at the documented ~880 TF
// source-level plateau for 2-barrier K-loop structures on gfx950).
// Structure: prep kernels split z (hi+lo f16, Sterbenz-exact residual) and
// cb*2^13 (exact pow2) into MFMA-fragment-ordered granule arrays; GEMM stages
// A through LDS once per block (global_load_lds w16), B direct global->VGPR;
// 128x128 block, 2x2 waves of 64x64, 16x16x32 MFMA (16 independent
// accumulators/wave — R21 proved 32x32 shape stalls on acc dependencies),
// 4 blocks/CU. dist = fp32(zsq - acc*2^-12): identical quantization to the
// numpy reference (fp32 bins ~3e-5 >> 3e-9 accumulation error); u64 packed-key
// (dist_bits<<32)|k lexicographic min == first-lowest-index argmin.
// Session lessons encoded: no device fences in hot kernels (R15); no
// sched_barrier order-pinning (R14/R16); compiler owns vmcnt (R17); BK=32 (R19).
#define KC 8192
#define NQ 8192
#define DD 256
#define NSTAGE 8
#define NT 64              // total k-tiles of 128 codes
#define MT 32              // A prep tiles (256 rows each)

typedef _Float16 f16;
typedef _Float16 half8 __attribute__((ext_vector_type(8)));
typedef float floatx4 __attribute__((ext_vector_type(4)));

// ---- workspace maps ----
#define WS_AH   0
#define WS_AL   4194304
#define WS_BH   8388608
#define WS_BL2  10485760
#define WS_PART2 12582912
#define WS_BL1  12582912
#define WS_PART1 16777216
#define WS_NEED_1PASS 20971520ull

// LDS: A stage buffer. Quad regions padded 2048->2064 B to stagger banks.
#define AQ 2064
#define AL_OFF (4 * AQ)            // 8256: lo region
#define SMEM_BYTES (8 * AQ)        // 16512

// ---- device helpers (R4..R20-verified bodies) ----
__device__ __forceinline__ void prep_b_body(const float* __restrict__ cb,
                                            f16* __restrict__ Bh, f16* __restrict__ Bl,
                                            int kofs, int gid) {
    int n = gid & 127;
    int q = (gid >> 7) & 3;
    int s = (gid >> 9) & 7;
    int ntl = gid >> 12;
    int K = kofs + ntl * 128 + n;
    int d0 = s * 32 + q * 8;
    const float4 v0 = *(const float4*)(cb + (size_t)K * DD + d0);
    const float4 v1 = *(const float4*)(cb + (size_t)K * DD + d0 + 4);
    float vv[8] = {v0.x, v0.y, v0.z, v0.w, v1.x, v1.y, v1.z, v1.w};
    half8 eh8, el8;
    #pragma unroll
    for (int j = 0; j < 8; ++j) {
        float e = vv[j] * 8192.0f;               // exact pow2 scale
        f16 h = (f16)e;
        eh8[j] = h;
        el8[j] = (f16)(e - (float)h);
    }
    *(half8*)(Bh + (size_t)gid * 8) = eh8;
    *(half8*)(Bl + (size_t)gid * 8) = el8;
}

// Vectorized A-prep (R20-verified): bit-identical granules, float4 along t.
__device__ __forceinline__ void prep_a_vec_body(const float* __restrict__ z,
                                                f16* __restrict__ Ah, f16* __restrict__ Al,
                                                int bid, int tid) {
    const int mt = bid >> 3;
    const int s  = bid & 7;
    const int q  = tid >> 6;
    const int lane = tid & 63;
    const int r0 = lane * 4;
    const int Q0 = mt * 256;
    const int b = Q0 >> 10;
    const int t0 = (Q0 & 1023) + r0;
    const float* zp = z + (size_t)b * (DD * 1024) + t0;
    const int d0 = s * 32 + q * 8;
    float4 v[8];
    #pragma unroll
    for (int j = 0; j < 8; ++j)
        v[j] = *(const float4*)(zp + (size_t)(d0 + j) * 1024);
    const size_t gbase = (((size_t)(mt * 8 + s) * 4 + q) * 256 + r0);
    #pragma unroll
    for (int dq = 0; dq < 4; ++dq) {
        half8 zh8, zl8;
        #pragma unroll
        for (int j = 0; j < 8; ++j) {
            float vv = (dq == 0) ? v[j].x : (dq == 1) ? v[j].y : (dq == 2) ? v[j].z : v[j].w;
            f16 h = (f16)vv;
            zh8[j] = h;
            zl8[j] = (f16)(vv - (float)h);       // exact fp32 residual
        }
        *(half8*)(Ah + (gbase + dq) * 8) = zh8;
        *(half8*)(Al + (gbase + dq) * 8) = zl8;
    }
}

__device__ __forceinline__ void zsq_body(const float* __restrict__ z,
                                         float* __restrict__ zsq, int q) {
    int b = q >> 10, t = q & 1023;
    const float* p = z + (size_t)b * (DD * 1024) + t;
    float s0 = 0.f, s1 = 0.f;
    #pragma unroll 8
    for (int d = 0; d < 128; ++d) { float v = p[(size_t)d * 1024]; s0 = fmaf(v, v, s0); }
    #pragma unroll 8
    for (int d = 128; d < 256; ++d) { float v = p[(size_t)d * 1024]; s1 = fmaf(v, v, s1); }
    zsq[q] = s0 + s1;    // identical chain to R1..R20 passers
}

// ---- fused prep: blocks [0,1024) B | [1024,1280) A-vec | [1280,1312) zsq ----
__global__ void vq_prep_all(const float* __restrict__ z, const float* __restrict__ cb,
                            f16* __restrict__ Ah, f16* __restrict__ Al,
                            f16* __restrict__ Bh, f16* __restrict__ Bl,
                            float* __restrict__ zsq) {
    int bid = blockIdx.x;
    int tid = threadIdx.x;
    if (bid < 1024) {
        prep_b_body(cb, Bh, Bl, 0, bid * 256 + tid);
    } else if (bid < 1280) {
        prep_a_vec_body(z, Ah, Al, bid - 1024, tid);
    } else {
        zsq_body(z, zsq, (bid - 1280) * 256 + tid);
    }
}

// standalone preps for the 2-pass fallback
__global__ void vq_prep_a(const float* __restrict__ z,
                          f16* __restrict__ Ah, f16* __restrict__ Al) {
    prep_a_vec_body(z, Ah, Al, blockIdx.x, threadIdx.x);
}
__global__ void vq_prep_b(const float* __restrict__ cb,
                          f16* __restrict__ Bh, f16* __restrict__ Bl, int kofs) {
    prep_b_body(cb, Bh, Bl, kofs, blockIdx.x * 256 + threadIdx.x);
}
__global__ void vq_zsq(const float* __restrict__ z, float* __restrict__ zsq) {
    zsq_body(z, zsq, blockIdx.x * 256 + threadIdx.x);
}

// ---- main GEMM (R18/R20-verified body): 128x128 block, 4 waves of 64x64,
//      A via LDS once/block, B direct-global; 4 blocks/CU ----
__global__ __launch_bounds__(256, 4)
void vq_gemm16(const f16* __restrict__ Ah, const f16* __restrict__ Al,
               const f16* __restrict__ Bh, const f16* __restrict__ Bl,
               const float* __restrict__ zsq, unsigned long long* __restrict__ part_p,
               int kofs) {
    // Swizzle (R12/R18-verified): per XCD, 8-ntl B chunks x 8 mh2 A tiles.
    const int flat = blockIdx.x;
    const int xcd = flat & 7;
    const int idx = flat >> 3;
    const int mh2 = xcd * 8 + ((idx >> 3) & 7);     // 0..63, 128-row tile
    const int ntl = (idx >> 6) * 8 + (idx & 7);     // 0..63 / 0..31
    const int tid = threadIdx.x;
    const int lane = tid & 63;
    const int wv = tid >> 6;
    const int wm = wv >> 1, wn = wv & 1;            // 2x2 waves of 64x64
    const int quad = lane >> 4;
    const int l16 = lane & 15;

    __shared__ __attribute__((aligned(16))) char smem[SMEM_BYTES];

    floatx4 acc[4][4];
    #pragma unroll
    for (int i = 0; i < 4; ++i)
        #pragma unroll
        for (int j = 0; j < 4; ++j) acc[i][j] = (floatx4)0.f;

    const int mt = mh2 >> 1;
    const int r0 = (mh2 & 1) * 128;
    const f16* Bpb = Bh + ((size_t)(ntl * 8) * 4 + quad) * 1024 + (size_t)(wn * 64 + l16) * 8;
    const f16* Blb = Bl + ((size_t)(ntl * 8) * 4 + quad) * 1024 + (size_t)(wn * 64 + l16) * 8;

    for (int s = 0; s < NSTAGE; ++s) {
        __syncthreads();   // previous stage's A fully consumed
        // ---- stage A into LDS: 16 x 1KB chunks (hi 8, lo 8), 4 per wave ----
        #pragma unroll
        for (int i = 0; i < 4; ++i) {
            int c = wv * 4 + i;                 // wave-uniform chunk id
            int hi = c >> 3;                    // 0: Ah, 1: Al
            int qd = (c >> 1) & 3;
            int hf = c & 1;
            const char* gsrc = (const char*)(hi ? Al : Ah)
                + (((size_t)(mt * 8 + s) * 4 + qd) * 4096) + (size_t)r0 * 16 + hf * 1024;
            int ldsoff = hi * AL_OFF + qd * AQ + hf * 1024;
            __builtin_amdgcn_global_load_lds(
                (const __attribute__((address_space(1))) void*)(gsrc + lane * 16),
                (__attribute__((address_space(3))) void*)(smem + ldsoff),
                16, 0, 0);
        }
        // ---- B fragments direct from global (issued before the barrier drain) ----
        half8 bhf[4], blf[4];
        {
            const f16* Bs  = Bpb + (size_t)s * 4096;
            const f16* Bls = Blb + (size_t)s * 4096;
            #pragma unroll
            for (int nj = 0; nj < 4; ++nj) {
                bhf[nj] = *(const half8*)(Bs + nj * 128);
                blf[nj] = *(const half8*)(Bls + nj * 128);
            }
        }
        __syncthreads();   // vmcnt(0) drain -> A staged, B in registers
        // ---- A fragments from LDS (DS pipe, no TA traffic) ----
        half8 av[4], aw[4];
        #pragma unroll
        for (int mi = 0; mi < 4; ++mi) {
            int ro = (wm * 64 + mi * 16 + l16) * 16;
            av[mi] = *(const half8*)(smem + quad * AQ + ro);
            aw[mi] = *(const half8*)(smem + AL_OFF + quad * AQ + ro);
        }
        // ---- term-major MFMA (16 independent between dependent pairs) ----
        #pragma unroll
        for (int mi = 0; mi < 4; ++mi)
            #pragma unroll
            for (int nj = 0; nj < 4; ++nj)
                acc[mi][nj] = __builtin_amdgcn_mfma_f32_16x16x32_f16(av[mi], bhf[nj], acc[mi][nj], 0, 0, 0);
        #pragma unroll
        for (int mi = 0; mi < 4; ++mi)
            #pragma unroll
            for (int nj = 0; nj < 4; ++nj)
                acc[mi][nj] = __builtin_amdgcn_mfma_f32_16x16x32_f16(av[mi], blf[nj], acc[mi][nj], 0, 0, 0);
        #pragma unroll
        for (int mi = 0; mi < 4; ++mi)
            #pragma unroll
            for (int nj = 0; nj < 4; ++nj)
                acc[mi][nj] = __builtin_amdgcn_mfma_f32_16x16x32_f16(aw[mi], bhf[nj], acc[mi][nj], 0, 0, 0);
    }

    // ---- epilogue (R12/R18-verified maps): dist quantization + 2-way LDS merge ----
    __syncthreads();                              // reuse smem for kbuf
    unsigned long long* kbuf = (unsigned long long*)smem;   // [2][128]
    const int kb = kofs + ntl * 128 + wn * 64;
    #pragma unroll
    for (int mi = 0; mi < 4; ++mi) {
        #pragma unroll
        for (int reg = 0; reg < 4; ++reg) {
            int qlocal = wm * 64 + mi * 16 + quad * 4 + reg;   // verified C/D map
            float zq = zsq[mh2 * 128 + qlocal];
            float bd = FLT_MAX; int bk = 0;
            #pragma unroll
            for (int nj = 0; nj < 4; ++nj) {        // ascending k: '<' keeps lowest
                float dd = zq - acc[mi][nj][reg] * 0x1p-12f;  // single fp32 rounding
                int kk = kb + nj * 16 + l16;
                if (dd < bd || (dd == bd && kk < bk)) { bd = dd; bk = kk; }
            }
            #pragma unroll
            for (int mm = 1; mm <= 8; mm <<= 1) {   // 16-lane butterfly, same q
                float od = __shfl_xor(bd, mm, 64);
                int ok = __shfl_xor(bk, mm, 64);
                if (od < bd || (od == bd && ok < bk)) { bd = od; bk = ok; }
            }
            if (l16 == 0)
                kbuf[wn * 128 + qlocal] =
                    ((unsigned long long)__float_as_uint(bd) << 32) | (unsigned int)bk;
        }
    }
    __syncthreads();
    if (tid < 128) {
        unsigned long long k0 = kbuf[tid];
        unsigned long long k1 = kbuf[128 + tid];
        unsigned long long key = (k1 < k0) ? k1 : k0;
        part_p[(size_t)ntl * NQ + mh2 * 128 + tid] = key;   // coalesced 1KB store
    }
}

__global__ void vq_reduce64(const unsigned long long* __restrict__ part,
                            int* __restrict__ out) {
    int q = blockIdx.x * 256 + threadIdx.x;
    unsigned long long best = part[q];
    #pragma unroll 8
    for (int s = 1; s < NT; ++s) {                  // coalesced per-row reads
        unsigned long long k2 = part[(size_t)s * NQ + q];
        if (k2 < best) best = k2;
    }
    out[q] = (int)(best & 0xFFFFFFFFull);
}

extern "C" void kernel_launch(void* const* d_in, const int* in_sizes, int n_in,
                              void* d_out, int out_size, void* d_ws, size_t ws_size,
                              hipStream_t stream) {
    const float* z  = (const float*)d_in[0];   // (8, 256, 1024) fp32
    const float* cb = (const float*)d_in[1];   // (8192, 256) fp32
    char* ws = (char*)d_ws;
    f16* Ah = (f16*)(ws + WS_AH);
    f16* Al = (f16*)(ws + WS_AL);
    // zsq parked in d_out (32 KB): read by gemm, overwritten by reduce.
    float* zsq = (float*)d_out;
    int* out = (int*)d_out;

    if (ws_size >= WS_NEED_1PASS) {
        f16* Bh = (f16*)(ws + WS_BH);
        f16* Bl = (f16*)(ws + WS_BL1);
        unsigned long long* part = (unsigned long long*)(ws + WS_PART1);
        vq_prep_all<<<1312, 256, 0, stream>>>(z, cb, Ah, Al, Bh, Bl, zsq);
        vq_gemm16<<<4096, 256, 0, stream>>>(Ah, Al, Bh, Bl, zsq, part, 0);
        vq_reduce64<<<NQ / 256, 256, 0, stream>>>(part, out);
    } else {
        // 2-pass fallback under the proven 16.875 MB floor (B buffer reused)
        f16* Bh = (f16*)(ws + WS_BH);
        f16* Bl = (f16*)(ws + WS_BL2);
        unsigned long long* part = (unsigned long long*)(ws + WS_PART2);
        vq_zsq<<<NQ / 256, 256, 0, stream>>>(z, zsq);
        vq_prep_a<<<256, 256, 0, stream>>>(z, Ah, Al);
        for (int p = 0; p < 2; ++p) {
            int kofs = p * 4096;
            vq_prep_b<<<512, 256, 0, stream>>>(cb, Bh, Bl, kofs);
            vq_gemm16<<<2048, 256, 0, stream>>>(Ah, Al, Bh, Bl, zsq,
                                                part + (size_t)p * 32 * NQ, kofs);
        }
        vq_reduce64<<<NQ / 256, 256, 0, stream>>>(part, out);
    }
}